// Round 13
// baseline (85.845 us; speedup 1.0000x reference)
//
#include <hip/hip_runtime.h>
#include <math.h>

#define CLS   4096      // row length C
#define KSEL  2048u     // k = round(C * 0.5)
#define TPB   256

typedef float f32x4 __attribute__((ext_vector_type(4)));

// LDS layout (bytes), total 10288:
//  h0   : u32[2048] @     0 ( 8192)  12-bit hist, single copy
//  cand : u32[512]  @  8192 ( 2048)  boundary-bin candidates (packed keys)
//  s_cnt u32 @10240 ; s_fr f32[8] @10244 -> 10276 (pad to 10288)
//  zero region = [0,10240) = 640 uint4 + s_cnt, under global-load latency
//  fallback aliases (h0/cand dead): s_flag u8[4096]@0 ; s_suf u32[256]@4096 ;
//    h1 u32[260]@5120 ; h2 u32[260]@6160 ; h3 u32[64]@7200
//
// Common path has ONLY 3 barriers: B0 (zero visible), B1 (hist+stats),
// B4 (cand gather). Scan and rank are wave-redundant (all 4 waves compute
// the identical result from shared LDS, broadcast in-register via ballot+shfl).

template<int SHIFT, int NBITS, int BPL>
__device__ __forceinline__ void radix_small(const float sc[16], unsigned* hist,
        int lane, unsigned& prefix, unsigned& kr, unsigned& cnt_eq)
{
    const unsigned msk = (1u << NBITS) - 1u;
    #pragma unroll
    for (int i = 0; i < 16; ++i) {
        unsigned u = __float_as_uint(sc[i]);
        if ((u >> (SHIFT + NBITS)) == (prefix >> (SHIFT + NBITS)))
            atomicAdd(&hist[(u >> SHIFT) & msk], 1u);
    }
    __syncthreads();
    unsigned c[BPL];
    if constexpr (BPL == 4) {
        uint4 x = *(const uint4*)&hist[lane * 4];
        c[0] = x.x; c[1] = x.y; c[2] = x.z; c[3] = x.w;
    } else {
        c[0] = hist[lane];
    }
    unsigned sfx[BPL + 1]; sfx[BPL] = 0;
    #pragma unroll
    for (int j = BPL - 1; j >= 0; --j) sfx[j] = sfx[j + 1] + c[j];
    const unsigned tot = sfx[0];
    unsigned s = tot;
    #pragma unroll
    for (int off = 1; off < 64; off <<= 1) {
        unsigned t = __shfl_down(s, off);
        if (lane + off < 64) s += t;
    }
    const unsigned Sx = s - tot;
    const bool has = (Sx < kr) && (kr <= Sx + tot);
    unsigned bin = 0, below = 0, ceq = 0;
    if (has) {
        #pragma unroll
        for (int j = 0; j < BPL; ++j)
            if (Sx + sfx[j] >= kr && Sx + sfx[j + 1] < kr) {
                bin = (unsigned)(lane * BPL + j);
                below = Sx + sfx[j + 1];
                ceq = c[j];
            }
    }
    unsigned long long m = __ballot(has);
    int src = (int)__builtin_ctzll(m);
    bin = __shfl(bin, src); below = __shfl(below, src); ceq = __shfl(ceq, src);
    prefix |= bin << SHIFT;
    kr -= below;
    cnt_eq = ceq;
}

__global__ __launch_bounds__(TPB) void proxy_gate_kernel(
    const float* __restrict__ token,
    const float* __restrict__ proxy,
    float* __restrict__ out)
{
    __shared__ __align__(16) unsigned char lds[10288];
    unsigned* h0    = (unsigned*)(lds);
    unsigned* cand  = (unsigned*)(lds + 8192);
    unsigned* s_cnt = (unsigned*)(lds + 10240);
    float*    s_fr  = (float*)   (lds + 10244);
    unsigned char* s_flag = lds;                    // fallback aliases (h0 dead)
    unsigned*      s_suf  = (unsigned*)(lds + 4096);
    unsigned*      h1     = (unsigned*)(lds + 5120);
    unsigned*      h2     = (unsigned*)(lds + 6160);
    unsigned*      h3     = (unsigned*)(lds + 7200);

    const int tid  = threadIdx.x;
    const int lane = tid & 63;
    const int wv   = tid >> 6;
    const size_t base = (size_t)blockIdx.x * CLS;
    const float4* t4 = (const float4*)(token + base);
    const float4* p4 = (const float4*)(proxy + base);
    f32x4* o4 = (f32x4*)(out + base);

    // ---- issue all global loads; zero h0+cand (+s_cnt) under their latency ----
    float4 tv[4], pv[4];
    #pragma unroll
    for (int i = 0; i < 4; ++i) { tv[i] = t4[i*TPB + tid]; pv[i] = p4[i*TPB + tid]; }
    {
        uint4 z = make_uint4(0u, 0u, 0u, 0u);
        uint4* zp = (uint4*)lds;
        #pragma unroll
        for (int m = 0; m < 3; ++m) { int idx = m*TPB + tid; if (idx < 640) zp[idx] = z; }
        if (tid == 0) *s_cnt = 0u;
    }

    float sc[16];
    float sum = 0.f, sumsq = 0.f;
    #pragma unroll
    for (int i = 0; i < 4; ++i) {
        float a;
        a = fabsf(tv[i].x*pv[i].x); sc[i*4+0]=a; sum+=a; sumsq+=a*a;
        a = fabsf(tv[i].y*pv[i].y); sc[i*4+1]=a; sum+=a; sumsq+=a*a;
        a = fabsf(tv[i].z*pv[i].z); sc[i*4+2]=a; sum+=a; sumsq+=a*a;
        a = fabsf(tv[i].w*pv[i].w); sc[i*4+3]=a; sum+=a; sumsq+=a*a;
    }
    __syncthreads();                                 // B0: zeroing visible

    // ---- pass 0 atomics (12-bit bins) + stats reduce ----
    #pragma unroll
    for (int i = 0; i < 16; ++i)
        atomicAdd(&h0[__float_as_uint(sc[i]) >> 20], 1u);
    #pragma unroll
    for (int off = 32; off > 0; off >>= 1) {
        sum   += __shfl_xor(sum, off);
        sumsq += __shfl_xor(sumsq, off);
    }
    if (lane == 0) { s_fr[wv] = sum; s_fr[4+wv] = sumsq; }
    __syncthreads();                                 // B1: atomics + stats visible

    const float tot_s = s_fr[0]+s_fr[1]+s_fr[2]+s_fr[3];
    const float tot_q = s_fr[4]+s_fr[5]+s_fr[6]+s_fr[7];
    const float mu = tot_s * (1.0f/CLS);
    float var = (tot_q - tot_s*mu) * (1.0f/(CLS-1));
    var = fmaxf(var, 0.0f);
    const float inv_sigma = 1.0f / fmaxf(sqrtf(var), 1e-6f);

    // ---- wave-redundant scan, ZERO barriers. Chunk w (256 bins), lane owns
    //      bins [w*256+lane*4, +4) read as one uint4 (16B/lane, conflict-free).
    unsigned kr = KSEL, bin = 0, cnt_eq = 0;
    {
        const uint4* h4 = (const uint4*)h0;
        unsigned g[8], S[8];
        #pragma unroll
        for (int w = 0; w < 8; ++w) {
            uint4 q = h4[w*64 + lane];
            g[w] = q.x + q.y + q.z + q.w;
        }
        #pragma unroll
        for (int w = 0; w < 8; ++w) {
            unsigned s = g[w];
            #pragma unroll
            for (int off = 1; off < 64; off <<= 1) {
                unsigned t = __shfl_down(s, off);
                if (lane + off < 64) s += t;
            }
            S[w] = s;                                // inclusive suffix within chunk
        }
        bool has = false;
        unsigned fbin = 0, fbelow = 0, fceq = 0, up = 0;
        #pragma unroll
        for (int w = 7; w >= 0; --w) {
            const unsigned Sx = up + S[w] - g[w];    // strictly above lane's group
            if (Sx < kr && kr <= Sx + g[w]) {        // boundary in this group
                uint4 q = h4[w*64 + lane];           // re-read (keeps regs lean)
                const unsigned c[4] = { q.x, q.y, q.z, q.w };
                unsigned r = Sx;
                #pragma unroll
                for (int j = 3; j >= 0; --j) {       // descending bin order
                    unsigned rn = r + c[j];
                    if (r < kr && kr <= rn) {
                        fbin = (unsigned)(w*256 + lane*4 + j);
                        fbelow = r; fceq = c[j]; has = true;
                    }
                    r = rn;
                }
            }
            up += __shfl(S[w], 0);                   // add chunk-w total
        }
        unsigned long long m = __ballot(has);        // exactly one lane
        int src = (int)__builtin_ctzll(m);
        bin    = __shfl(fbin, src);
        kr    -= __shfl(fbelow, src);
        cnt_eq = __shfl(fceq, src);
    }

    // ---- gather boundary-bin candidates: key=(u<<12)|(4095-idx), distinct ----
    {
        unsigned cmask = 0, lc = 0;
        #pragma unroll
        for (int ii = 0; ii < 16; ++ii) {
            bool cnd = ((__float_as_uint(sc[ii]) >> 20) == bin);
            cmask |= ((unsigned)cnd) << ii;
            lc += (unsigned)cnd;
        }
        unsigned inc = lc;
        #pragma unroll
        for (int off = 1; off < 64; off <<= 1) {
            unsigned t = __shfl_up(inc, off);
            if (lane >= off) inc += t;
        }
        const unsigned wtot = __shfl(inc, 63);
        unsigned wbase = 0;
        if (lane == 0) wbase = atomicAdd(s_cnt, wtot);
        wbase = __shfl(wbase, 0);
        unsigned p = wbase + (inc - lc);
        #pragma unroll
        for (int ii = 0; ii < 16; ++ii) {
            if ((cmask >> ii) & 1u) {
                unsigned u = __float_as_uint(sc[ii]);
                unsigned idx = (unsigned)((ii >> 2)*1024 + tid*4 + (ii & 3));
                if (p < 512u) cand[p] = (u << 12) | (4095u - idx);
                ++p;
            }
        }
    }
    __syncthreads();                                 // B4: cand + s_cnt visible
    const unsigned cnt = *s_cnt;
    const bool cand_mode = (cnt <= 512u);

    unsigned Kth = 0;
    float thr = 0.f; bool tie_rare = false;
    if (cand_mode) {
        // ---- wave-redundant rank, ZERO barriers: each wave ranks all cands,
        //      winner broadcast in-register. cand zero-padding can't inflate
        //      rank (0 > key is false). ----
        unsigned myK = 0; bool found = false;
        const uint4* c4 = (const uint4*)cand;
        const unsigned nq = (cnt + 3u) >> 2;
        for (unsigned slot = (unsigned)lane; slot < cnt; slot += 64u) {
            const unsigned my = cand[slot];
            unsigned rank = 0;
            for (unsigned q = 0; q < nq; ++q) {      // same-address broadcast reads
                uint4 v = c4[q];
                rank += (unsigned)(v.x > my) + (unsigned)(v.y > my)
                      + (unsigned)(v.z > my) + (unsigned)(v.w > my);
            }
            if (rank == kr - 1u) { myK = my; found = true; }
        }
        unsigned long long m = __ballot(found);      // exactly one lane
        int src = (int)__builtin_ctzll(m);
        Kth = __shfl(myK, src);
    } else {
        // ---- rare fallback (cnt>512): radix chain + stable tie ranking ----
        unsigned prefix = bin << 20;
        {
            unsigned* hz = (unsigned*)(lds + 5120);  // zero h1/h2/h3 (h0 dead)
            #pragma unroll
            for (int m = 0; m < 3; ++m) { int ix = m*TPB + tid; if (ix < 584) hz[ix] = 0u; }
        }
        __syncthreads();
        radix_small<12, 8, 4>(sc, h1, lane, prefix, kr, cnt_eq);
        radix_small< 4, 8, 4>(sc, h2, lane, prefix, kr, cnt_eq);
        radix_small< 0, 4, 1>(sc, h3, lane, prefix, kr, cnt_eq);
        thr = __uint_as_float(prefix);
        tie_rare = (cnt_eq != kr);
        if (tie_rare) {
            #pragma unroll
            for (int i = 0; i < 4; ++i)
                #pragma unroll
                for (int c2 = 0; c2 < 4; ++c2)
                    s_flag[i*1024 + tid*4 + c2] = (sc[i*4+c2] == thr) ? 1 : 0;
            __syncthreads();
            unsigned lc = 0;
            unsigned char mf[16];
            #pragma unroll
            for (int m = 0; m < 16; ++m) { mf[m] = s_flag[tid*16 + m]; lc += mf[m]; }
            s_suf[tid] = lc;
            __syncthreads();
            #pragma unroll
            for (int off = 1; off < 256; off <<= 1) {
                unsigned w = s_suf[tid] + ((tid >= off) ? s_suf[tid - off] : 0u);
                __syncthreads();
                s_suf[tid] = w;
                __syncthreads();
            }
            unsigned r2 = s_suf[tid] - lc;
            #pragma unroll
            for (int m = 0; m < 16; ++m) {
                if (mf[m]) { s_flag[tid*16 + m] = (r2 < kr) ? 2 : 0; ++r2; }
            }
        }
        __syncthreads();                             // flags visible (rare path only)
    }

    // ---- gate + store: sigmoid via exp2+raw rcp; hard via 32-bit compares ----
    const float A  = -inv_sigma * 1.44269504f;       // exp(-z) = 2^(s*A + Bc)
    const float Bc = -mu * A;
    const unsigned rbase = 4095u - 4u*(unsigned)tid; // 4095-idx = rbase-1024i-c2
    #pragma unroll
    for (int i = 0; i < 4; ++i) {
        const float tkc[4] = { tv[i].x, tv[i].y, tv[i].z, tv[i].w };
        f32x4 rv;
        #pragma unroll
        for (int c2 = 0; c2 < 4; ++c2) {
            const float s = sc[i*4+c2];
            const float e2 = __builtin_amdgcn_exp2f(fmaf(s, A, Bc));
            const float soft = __builtin_amdgcn_rcpf(1.0f + e2);
            const unsigned u = __float_as_uint(s);
            bool hard;
            if (cand_mode) {
                const unsigned e = u >> 20;
                const unsigned packed = (u << 12) | (rbase - 1024u*(unsigned)i - (unsigned)c2);
                hard = (e > bin) || ((e == bin) && (packed >= Kth));
            } else if (tie_rare) {
                hard = (s > thr) || ((s == thr) && (s_flag[i*1024 + tid*4 + c2] == 2));
            } else {
                hard = (s >= thr);
            }
            rv[c2] = tkc[c2] * (hard ? 1.0f : soft);
        }
        __builtin_nontemporal_store(rv, &o4[i*TPB + tid]);
    }
}

extern "C" void kernel_launch(void* const* d_in, const int* in_sizes, int n_in,
                              void* d_out, int out_size, void* d_ws, size_t ws_size,
                              hipStream_t stream) {
    const float* token = (const float*)d_in[0];
    const float* proxy = (const float*)d_in[1];
    float* outp = (float*)d_out;
    const int B = in_sizes[0] / CLS;
    hipLaunchKernelGGL(proxy_gate_kernel, dim3(B), dim3(TPB), 0, stream,
                       token, proxy, outp);
}

// Round 14
// 77.173 us; speedup vs baseline: 1.1124x; 1.1124x over previous
//
#include <hip/hip_runtime.h>
#include <math.h>

#define CLS   4096      // row length C
#define KSEL  2048u     // k = round(C * 0.5)
#define TPB   256

typedef float f32x4 __attribute__((ext_vector_type(4)));

// LDS layout (bytes), total 18512:
//  h0   : u32[2][2048] @     0 (16384)  12-bit hist, 2 copies (quarter-wave split)
//  cand : u32[512]     @ 16384 ( 2048)  boundary-bin candidates (packed keys)
//  s_cnt u32 @18432 ; s_wt u32[4] @18436 ; s_bc u32[3] @18452 ; s_fr f32[8] @18468
//  zero region = [0,18432) = 1152 uint4 + s_cnt, under global-load latency
//  fallback aliases (h0/cand dead): s_flag u8[4096]@0 ; s_suf u32[256]@4096 ;
//    h1 u32[260]@5120 ; h2 u32[260]@6160 ; h3 u32[64]@7200
//
// Common path: 5 barriers (B0 zero, B1 hist+stats, B2/B3 scan, B4 gather).
// Rank is wave-redundant in-register (cheap: ~18 broadcast uint4 reads), no B5.

template<int SHIFT, int NBITS, int BPL>
__device__ __forceinline__ void radix_small(const float sc[16], unsigned* hist,
        int lane, unsigned& prefix, unsigned& kr, unsigned& cnt_eq)
{
    const unsigned msk = (1u << NBITS) - 1u;
    #pragma unroll
    for (int i = 0; i < 16; ++i) {
        unsigned u = __float_as_uint(sc[i]);
        if ((u >> (SHIFT + NBITS)) == (prefix >> (SHIFT + NBITS)))
            atomicAdd(&hist[(u >> SHIFT) & msk], 1u);
    }
    __syncthreads();
    unsigned c[BPL];
    if constexpr (BPL == 4) {
        uint4 x = *(const uint4*)&hist[lane * 4];
        c[0] = x.x; c[1] = x.y; c[2] = x.z; c[3] = x.w;
    } else {
        c[0] = hist[lane];
    }
    unsigned sfx[BPL + 1]; sfx[BPL] = 0;
    #pragma unroll
    for (int j = BPL - 1; j >= 0; --j) sfx[j] = sfx[j + 1] + c[j];
    const unsigned tot = sfx[0];
    unsigned s = tot;
    #pragma unroll
    for (int off = 1; off < 64; off <<= 1) {
        unsigned t = __shfl_down(s, off);
        if (lane + off < 64) s += t;
    }
    const unsigned Sx = s - tot;
    const bool has = (Sx < kr) && (kr <= Sx + tot);
    unsigned bin = 0, below = 0, ceq = 0;
    if (has) {
        #pragma unroll
        for (int j = 0; j < BPL; ++j)
            if (Sx + sfx[j] >= kr && Sx + sfx[j + 1] < kr) {
                bin = (unsigned)(lane * BPL + j);
                below = Sx + sfx[j + 1];
                ceq = c[j];
            }
    }
    unsigned long long m = __ballot(has);
    int src = (int)__builtin_ctzll(m);
    bin = __shfl(bin, src); below = __shfl(below, src); ceq = __shfl(ceq, src);
    prefix |= bin << SHIFT;
    kr -= below;
    cnt_eq = ceq;
}

__global__ __launch_bounds__(TPB) void proxy_gate_kernel(
    const float* __restrict__ token,
    const float* __restrict__ proxy,
    float* __restrict__ out)
{
    __shared__ __align__(16) unsigned char lds[18512];
    unsigned* h0    = (unsigned*)(lds);
    unsigned* cand  = (unsigned*)(lds + 16384);
    unsigned* s_cnt = (unsigned*)(lds + 18432);
    unsigned* s_wt  = (unsigned*)(lds + 18436);
    unsigned* s_bc  = (unsigned*)(lds + 18452);
    float*    s_fr  = (float*)   (lds + 18468);
    unsigned char* s_flag = lds;                    // fallback aliases (h0 dead)
    unsigned*      s_suf  = (unsigned*)(lds + 4096);
    unsigned*      h1     = (unsigned*)(lds + 5120);
    unsigned*      h2     = (unsigned*)(lds + 6160);
    unsigned*      h3     = (unsigned*)(lds + 7200);

    const int tid  = threadIdx.x;
    const int lane = tid & 63;
    const int wv   = tid >> 6;
    const size_t base = (size_t)blockIdx.x * CLS;
    const float4* t4 = (const float4*)(token + base);
    const float4* p4 = (const float4*)(proxy + base);
    f32x4* o4 = (f32x4*)(out + base);

    // ---- issue all global loads; zero h0+cand (+s_cnt) under their latency ----
    float4 tv[4], pv[4];
    #pragma unroll
    for (int i = 0; i < 4; ++i) { tv[i] = t4[i*TPB + tid]; pv[i] = p4[i*TPB + tid]; }
    {
        uint4 z = make_uint4(0u, 0u, 0u, 0u);
        uint4* zp = (uint4*)lds;
        #pragma unroll
        for (int m = 0; m < 5; ++m) { int idx = m*TPB + tid; if (idx < 1152) zp[idx] = z; }
        if (tid == 0) *s_cnt = 0u;
    }

    float sc[16];
    float sum = 0.f, sumsq = 0.f;
    #pragma unroll
    for (int i = 0; i < 4; ++i) {
        float a;
        a = fabsf(tv[i].x*pv[i].x); sc[i*4+0]=a; sum+=a; sumsq+=a*a;
        a = fabsf(tv[i].y*pv[i].y); sc[i*4+1]=a; sum+=a; sumsq+=a*a;
        a = fabsf(tv[i].z*pv[i].z); sc[i*4+2]=a; sum+=a; sumsq+=a*a;
        a = fabsf(tv[i].w*pv[i].w); sc[i*4+3]=a; sum+=a; sumsq+=a*a;
    }
    __syncthreads();                                 // B0: zeroing visible

    // ---- pass 0 atomics (12-bit bins, 2 copies, quarter-wave split) + stats ----
    {
        unsigned* h0c = h0 + ((tid & 4) ? 2048 : 0);
        #pragma unroll
        for (int i = 0; i < 16; ++i)
            atomicAdd(&h0c[__float_as_uint(sc[i]) >> 20], 1u);
    }
    #pragma unroll
    for (int off = 32; off > 0; off >>= 1) {
        sum   += __shfl_xor(sum, off);
        sumsq += __shfl_xor(sumsq, off);
    }
    if (lane == 0) { s_fr[wv] = sum; s_fr[4+wv] = sumsq; }
    __syncthreads();                                 // B1: atomics + stats visible

    const float tot_s = s_fr[0]+s_fr[1]+s_fr[2]+s_fr[3];
    const float tot_q = s_fr[4]+s_fr[5]+s_fr[6]+s_fr[7];
    const float mu = tot_s * (1.0f/CLS);
    float var = (tot_q - tot_s*mu) * (1.0f/(CLS-1));
    var = fmaxf(var, 0.0f);
    const float inv_sigma = 1.0f / fmaxf(sqrtf(var), 1e-6f);

    // ---- pass 0 scan: thread t owns bins [8t,8t+8), both copies summed ----
    unsigned kr = KSEL;
    {
        uint4 x0 = *(const uint4*)&h0[tid*8];
        uint4 x1 = *(const uint4*)&h0[tid*8 + 4];
        uint4 y0 = *(const uint4*)&h0[2048 + tid*8];
        uint4 y1 = *(const uint4*)&h0[2048 + tid*8 + 4];
        unsigned c[8] = { x0.x+y0.x, x0.y+y0.y, x0.z+y0.z, x0.w+y0.w,
                          x1.x+y1.x, x1.y+y1.y, x1.z+y1.z, x1.w+y1.w };
        unsigned sfx[9]; sfx[8] = 0;
        #pragma unroll
        for (int j = 7; j >= 0; --j) sfx[j] = sfx[j+1] + c[j];
        const unsigned tot = sfx[0];
        unsigned s = tot;
        #pragma unroll
        for (int off = 1; off < 64; off <<= 1) {
            unsigned t = __shfl_down(s, off);
            if (lane + off < 64) s += t;
        }
        if (lane == 0) s_wt[wv] = s;
        __syncthreads();                             // B2
        unsigned addhi = 0;
        #pragma unroll
        for (int w2 = 0; w2 < 4; ++w2) if (w2 > wv) addhi += s_wt[w2];
        const unsigned Sx = (s - tot) + addhi;
        if (Sx < kr && kr <= Sx + tot) {
            #pragma unroll
            for (int j = 0; j < 8; ++j)
                if (Sx + sfx[j] >= kr && Sx + sfx[j+1] < kr) {
                    s_bc[0] = (unsigned)(tid*8 + j);
                    s_bc[1] = Sx + sfx[j+1];
                    s_bc[2] = c[j];
                }
        }
        __syncthreads();                             // B3
        kr -= s_bc[1];
    }
    const unsigned bin = s_bc[0];
    unsigned cnt_eq = s_bc[2];

    // ---- gather boundary-bin candidates: key=(u<<12)|(4095-idx), distinct ----
    {
        unsigned cmask = 0, lc = 0;
        #pragma unroll
        for (int ii = 0; ii < 16; ++ii) {
            bool cnd = ((__float_as_uint(sc[ii]) >> 20) == bin);
            cmask |= ((unsigned)cnd) << ii;
            lc += (unsigned)cnd;
        }
        unsigned inc = lc;
        #pragma unroll
        for (int off = 1; off < 64; off <<= 1) {
            unsigned t = __shfl_up(inc, off);
            if (lane >= off) inc += t;
        }
        const unsigned wtot = __shfl(inc, 63);
        unsigned wbase = 0;
        if (lane == 0) wbase = atomicAdd(s_cnt, wtot);
        wbase = __shfl(wbase, 0);
        unsigned p = wbase + (inc - lc);
        #pragma unroll
        for (int ii = 0; ii < 16; ++ii) {
            if ((cmask >> ii) & 1u) {
                unsigned u = __float_as_uint(sc[ii]);
                unsigned idx = (unsigned)((ii >> 2)*1024 + tid*4 + (ii & 3));
                if (p < 512u) cand[p] = (u << 12) | (4095u - idx);
                ++p;
            }
        }
    }
    __syncthreads();                                 // B4: cand + s_cnt visible
    const unsigned cnt = *s_cnt;
    const bool cand_mode = (cnt <= 512u);            // block-uniform

    unsigned Kth = 0;
    float thr = 0.f; bool tie_rare = false;
    if (cand_mode) {
        // ---- wave-redundant rank, ZERO barriers: each wave ranks all cands
        //      (broadcast uint4 reads), winner broadcast via ballot+shfl.
        //      cand zero-padding can't inflate rank (0 > key is false). ----
        unsigned myK = 0; bool found = false;
        const uint4* c4 = (const uint4*)cand;
        const unsigned nq = (cnt + 3u) >> 2;
        for (unsigned slot = (unsigned)lane; slot < cnt; slot += 64u) {
            const unsigned my = cand[slot];
            unsigned rank = 0;
            for (unsigned q = 0; q < nq; ++q) {
                uint4 v = c4[q];
                rank += (unsigned)(v.x > my) + (unsigned)(v.y > my)
                      + (unsigned)(v.z > my) + (unsigned)(v.w > my);
            }
            if (rank == kr - 1u) { myK = my; found = true; }
        }
        unsigned long long m = __ballot(found);      // exactly one lane block-wide;
        int src = (int)__builtin_ctzll(m);           // per-wave: that wave's copy
        Kth = __shfl(myK, src);
    } else {
        // ---- rare fallback (cnt>512): radix chain + stable tie ranking ----
        unsigned prefix = bin << 20;
        {
            unsigned* hz = (unsigned*)(lds + 5120);  // zero h1/h2/h3 (h0 dead)
            #pragma unroll
            for (int m = 0; m < 3; ++m) { int ix = m*TPB + tid; if (ix < 584) hz[ix] = 0u; }
        }
        __syncthreads();
        radix_small<12, 8, 4>(sc, h1, lane, prefix, kr, cnt_eq);
        radix_small< 4, 8, 4>(sc, h2, lane, prefix, kr, cnt_eq);
        radix_small< 0, 4, 1>(sc, h3, lane, prefix, kr, cnt_eq);
        thr = __uint_as_float(prefix);
        tie_rare = (cnt_eq != kr);
        if (tie_rare) {
            #pragma unroll
            for (int i = 0; i < 4; ++i)
                #pragma unroll
                for (int c2 = 0; c2 < 4; ++c2)
                    s_flag[i*1024 + tid*4 + c2] = (sc[i*4+c2] == thr) ? 1 : 0;
            __syncthreads();
            unsigned lc = 0;
            unsigned char mf[16];
            #pragma unroll
            for (int m = 0; m < 16; ++m) { mf[m] = s_flag[tid*16 + m]; lc += mf[m]; }
            s_suf[tid] = lc;
            __syncthreads();
            #pragma unroll
            for (int off = 1; off < 256; off <<= 1) {
                unsigned w = s_suf[tid] + ((tid >= off) ? s_suf[tid - off] : 0u);
                __syncthreads();
                s_suf[tid] = w;
                __syncthreads();
            }
            unsigned r2 = s_suf[tid] - lc;
            #pragma unroll
            for (int m = 0; m < 16; ++m) {
                if (mf[m]) { s_flag[tid*16 + m] = (r2 < kr) ? 2 : 0; ++r2; }
            }
        }
        __syncthreads();                             // flags visible (rare path only)
    }

    // ---- gate + store: sigmoid via exp2+raw rcp; hard via 32-bit compares ----
    const float A  = -inv_sigma * 1.44269504f;       // exp(-z) = 2^(s*A + Bc)
    const float Bc = -mu * A;
    const unsigned rbase = 4095u - 4u*(unsigned)tid; // 4095-idx = rbase-1024i-c2
    #pragma unroll
    for (int i = 0; i < 4; ++i) {
        const float tkc[4] = { tv[i].x, tv[i].y, tv[i].z, tv[i].w };
        f32x4 rv;
        #pragma unroll
        for (int c2 = 0; c2 < 4; ++c2) {
            const float s = sc[i*4+c2];
            const float e2 = __builtin_amdgcn_exp2f(fmaf(s, A, Bc));
            const float soft = __builtin_amdgcn_rcpf(1.0f + e2);
            const unsigned u = __float_as_uint(s);
            bool hard;
            if (cand_mode) {
                const unsigned e = u >> 20;
                const unsigned packed = (u << 12) | (rbase - 1024u*(unsigned)i - (unsigned)c2);
                hard = (e > bin) || ((e == bin) && (packed >= Kth));
            } else if (tie_rare) {
                hard = (s > thr) || ((s == thr) && (s_flag[i*1024 + tid*4 + c2] == 2));
            } else {
                hard = (s >= thr);
            }
            rv[c2] = tkc[c2] * (hard ? 1.0f : soft);
        }
        __builtin_nontemporal_store(rv, &o4[i*TPB + tid]);
    }
}

extern "C" void kernel_launch(void* const* d_in, const int* in_sizes, int n_in,
                              void* d_out, int out_size, void* d_ws, size_t ws_size,
                              hipStream_t stream) {
    const float* token = (const float*)d_in[0];
    const float* proxy = (const float*)d_in[1];
    float* outp = (float*)d_out;
    const int B = in_sizes[0] / CLS;
    hipLaunchKernelGGL(proxy_gate_kernel, dim3(B), dim3(TPB), 0, stream,
                       token, proxy, outp);
}

// Round 15
// 71.619 us; speedup vs baseline: 1.1986x; 1.0775x over previous
//
#include <hip/hip_runtime.h>
#include <math.h>

#define CLS   4096      // row length C
#define KSEL  2048u     // k = round(C * 0.5)
#define TPB   256

typedef float f32x4 __attribute__((ext_vector_type(4)));

// R10 skeleton (67.5 us best) + s_setprio around the selection chain.
// LDS layout (bytes), total 10304:
//  h0   : u32[2048] @     0 ( 8192)  12-bit hist, single copy, plain layout
//  cand : u32[512]  @  8192 ( 2048)  boundary-bin candidates (packed keys)
//  s_cnt @10240 ; s_wt u32[4] @10244 ; s_bc u32[3] @10260 ; s_fr f32[8] @10272
//  zero-per-row = [0,10240) = 640 uint4 + s_cnt (under global-load latency)
//  fallback aliases (h0/cand dead): s_flag u8[4096]@0 ; s_suf u32[256]@4096 ;
//    h1 u32[260]@5120 ; h2 u32[260]@6160 ; h3 u32[64]@7200

template<int SHIFT, int NBITS, int BPL>
__device__ __forceinline__ void radix_small(const float sc[16], unsigned* hist,
        int lane, unsigned& prefix, unsigned& kr, unsigned& cnt_eq)
{
    const unsigned msk = (1u << NBITS) - 1u;
    #pragma unroll
    for (int i = 0; i < 16; ++i) {
        unsigned u = __float_as_uint(sc[i]);
        if ((u >> (SHIFT + NBITS)) == (prefix >> (SHIFT + NBITS)))
            atomicAdd(&hist[(u >> SHIFT) & msk], 1u);
    }
    __syncthreads();
    unsigned c[BPL];
    if constexpr (BPL == 4) {
        uint4 x = *(const uint4*)&hist[lane * 4];
        c[0] = x.x; c[1] = x.y; c[2] = x.z; c[3] = x.w;
    } else {
        c[0] = hist[lane];
    }
    unsigned sfx[BPL + 1]; sfx[BPL] = 0;
    #pragma unroll
    for (int j = BPL - 1; j >= 0; --j) sfx[j] = sfx[j + 1] + c[j];
    const unsigned tot = sfx[0];
    unsigned s = tot;
    #pragma unroll
    for (int off = 1; off < 64; off <<= 1) {
        unsigned t = __shfl_down(s, off);
        if (lane + off < 64) s += t;
    }
    const unsigned Sx = s - tot;
    const bool has = (Sx < kr) && (kr <= Sx + tot);
    unsigned bin = 0, below = 0, ceq = 0;
    if (has) {
        #pragma unroll
        for (int j = 0; j < BPL; ++j)
            if (Sx + sfx[j] >= kr && Sx + sfx[j + 1] < kr) {
                bin = (unsigned)(lane * BPL + j);
                below = Sx + sfx[j + 1];
                ceq = c[j];
            }
    }
    unsigned long long m = __ballot(has);
    int src = (int)__builtin_ctzll(m);
    bin = __shfl(bin, src); below = __shfl(below, src); ceq = __shfl(ceq, src);
    prefix |= bin << SHIFT;
    kr -= below;
    cnt_eq = ceq;
}

__global__ __launch_bounds__(TPB) void proxy_gate_kernel(
    const float* __restrict__ token,
    const float* __restrict__ proxy,
    float* __restrict__ out)
{
    __shared__ __align__(16) unsigned char lds[10304];
    unsigned* h0    = (unsigned*)(lds);
    unsigned* cand  = (unsigned*)(lds + 8192);
    unsigned* s_cnt = (unsigned*)(lds + 10240);
    unsigned* s_wt  = (unsigned*)(lds + 10244);
    unsigned* s_bc  = (unsigned*)(lds + 10260);
    float*    s_fr  = (float*)   (lds + 10272);
    unsigned char* s_flag = lds;                    // fallback aliases (h0 dead)
    unsigned*      s_suf  = (unsigned*)(lds + 4096);
    unsigned*      h1     = (unsigned*)(lds + 5120);
    unsigned*      h2     = (unsigned*)(lds + 6160);
    unsigned*      h3     = (unsigned*)(lds + 7200);

    const int tid  = threadIdx.x;
    const int lane = tid & 63;
    const int wv   = tid >> 6;
    const size_t base = (size_t)blockIdx.x * CLS;
    const float4* t4 = (const float4*)(token + base);
    const float4* p4 = (const float4*)(proxy + base);
    f32x4* o4 = (f32x4*)(out + base);

    // ---- issue all global loads; zero h0+cand (+s_cnt) under their latency ----
    float4 tv[4], pv[4];
    #pragma unroll
    for (int i = 0; i < 4; ++i) { tv[i] = t4[i*TPB + tid]; pv[i] = p4[i*TPB + tid]; }
    {
        uint4 z = make_uint4(0u, 0u, 0u, 0u);
        uint4* zp = (uint4*)lds;
        #pragma unroll
        for (int m = 0; m < 3; ++m) { int idx = m*TPB + tid; if (idx < 640) zp[idx] = z; }
        if (tid == 0) *s_cnt = 0u;
    }

    float sc[16];
    float sum = 0.f, sumsq = 0.f;
    #pragma unroll
    for (int i = 0; i < 4; ++i) {
        float a;
        a = fabsf(tv[i].x*pv[i].x); sc[i*4+0]=a; sum+=a; sumsq+=a*a;
        a = fabsf(tv[i].y*pv[i].y); sc[i*4+1]=a; sum+=a; sumsq+=a*a;
        a = fabsf(tv[i].z*pv[i].z); sc[i*4+2]=a; sum+=a; sumsq+=a*a;
        a = fabsf(tv[i].w*pv[i].w); sc[i*4+3]=a; sum+=a; sumsq+=a*a;
    }
    __syncthreads();                                 // B0: zeroing visible

    // ---- pass 0 atomics (12-bit bins, single copy, plain addr) + stats ----
    #pragma unroll
    for (int i = 0; i < 16; ++i)
        atomicAdd(&h0[__float_as_uint(sc[i]) >> 20], 1u);
    #pragma unroll
    for (int off = 32; off > 0; off >>= 1) {
        sum   += __shfl_xor(sum, off);
        sumsq += __shfl_xor(sumsq, off);
    }
    if (lane == 0) { s_fr[wv] = sum; s_fr[4+wv] = sumsq; }
    __syncthreads();                                 // B1: atomics + stats visible

    // Selection chain is the latency-critical serial section: boost priority so
    // the CU scheduler favors it over co-resident blocks' bulk load phases
    // (independent de-phased blocks — the m191-style setprio regime).
    __builtin_amdgcn_s_setprio(1);

    const float tot_s = s_fr[0]+s_fr[1]+s_fr[2]+s_fr[3];
    const float tot_q = s_fr[4]+s_fr[5]+s_fr[6]+s_fr[7];
    const float mu = tot_s * (1.0f/CLS);
    float var = (tot_q - tot_s*mu) * (1.0f/(CLS-1));
    var = fmaxf(var, 0.0f);
    const float inv_sigma = 1.0f / fmaxf(sqrtf(var), 1e-6f);

    // ---- pass 0 scan: thread t owns bins [8t,8t+8) ----
    unsigned kr = KSEL;
    {
        uint4 x0 = *(const uint4*)&h0[tid*8];
        uint4 x1 = *(const uint4*)&h0[tid*8 + 4];
        unsigned c[8] = { x0.x, x0.y, x0.z, x0.w, x1.x, x1.y, x1.z, x1.w };
        unsigned sfx[9]; sfx[8] = 0;
        #pragma unroll
        for (int j = 7; j >= 0; --j) sfx[j] = sfx[j+1] + c[j];
        const unsigned tot = sfx[0];
        unsigned s = tot;
        #pragma unroll
        for (int off = 1; off < 64; off <<= 1) {
            unsigned t = __shfl_down(s, off);
            if (lane + off < 64) s += t;
        }
        if (lane == 0) s_wt[wv] = s;
        __syncthreads();                             // B2
        unsigned addhi = 0;
        #pragma unroll
        for (int w2 = 0; w2 < 4; ++w2) if (w2 > wv) addhi += s_wt[w2];
        const unsigned Sx = (s - tot) + addhi;
        if (Sx < kr && kr <= Sx + tot) {
            #pragma unroll
            for (int j = 0; j < 8; ++j)
                if (Sx + sfx[j] >= kr && Sx + sfx[j+1] < kr) {
                    s_bc[0] = (unsigned)(tid*8 + j);
                    s_bc[1] = Sx + sfx[j+1];
                    s_bc[2] = c[j];
                }
        }
        __syncthreads();                             // B3
        kr -= s_bc[1];
    }
    const unsigned bin = s_bc[0];
    unsigned cnt_eq = s_bc[2];

    // ---- gather boundary-bin candidates: key=(u<<12)|(4095-idx), distinct ----
    {
        unsigned cmask = 0, lc = 0;
        #pragma unroll
        for (int ii = 0; ii < 16; ++ii) {
            bool cnd = ((__float_as_uint(sc[ii]) >> 20) == bin);
            cmask |= ((unsigned)cnd) << ii;
            lc += (unsigned)cnd;
        }
        unsigned inc = lc;
        #pragma unroll
        for (int off = 1; off < 64; off <<= 1) {
            unsigned t = __shfl_up(inc, off);
            if (lane >= off) inc += t;
        }
        const unsigned wtot = __shfl(inc, 63);
        unsigned wbase = 0;
        if (lane == 0) wbase = atomicAdd(s_cnt, wtot);
        wbase = __shfl(wbase, 0);
        unsigned p = wbase + (inc - lc);
        #pragma unroll
        for (int ii = 0; ii < 16; ++ii) {
            if ((cmask >> ii) & 1u) {
                unsigned u = __float_as_uint(sc[ii]);
                unsigned idx = (unsigned)((ii >> 2)*1024 + tid*4 + (ii & 3));
                if (p < 512u) cand[p] = (u << 12) | (4095u - idx);
                ++p;
            }
        }
    }
    __syncthreads();                                 // B4
    const unsigned cnt = *s_cnt;
    const bool cand_mode = (cnt <= 512u);

    float thr = 0.f; bool tie_rare = false;
    if (cand_mode) {
        // ---- cooperative rank: thread handles cand slots tid, tid+256 ----
        #pragma unroll
        for (int rpt = 0; rpt < 2; ++rpt) {
            const unsigned slot = (unsigned)tid + (unsigned)rpt*256u;
            if (slot < cnt) {
                const unsigned my = cand[slot];
                unsigned rank = 0;
                const uint4* c4 = (const uint4*)cand;
                const unsigned nq = (cnt + 3u) >> 2;
                for (unsigned q = 0; q < nq; ++q) {  // same-address broadcast reads
                    uint4 v = c4[q];
                    rank += (unsigned)(v.x > my) + (unsigned)(v.y > my)
                          + (unsigned)(v.z > my) + (unsigned)(v.w > my);
                }
                if (rank == kr - 1u) s_bc[0] = my;   // unique: keys distinct
            }
        }
    } else {
        // ---- rare fallback (cnt>512): radix chain + stable tie ranking ----
        unsigned prefix = bin << 20;
        {
            unsigned* hz = (unsigned*)(lds + 5120);  // zero h1/h2/h3 (h0 dead)
            #pragma unroll
            for (int m = 0; m < 3; ++m) { int ix = m*TPB + tid; if (ix < 584) hz[ix] = 0u; }
        }
        __syncthreads();
        radix_small<12, 8, 4>(sc, h1, lane, prefix, kr, cnt_eq);
        radix_small< 4, 8, 4>(sc, h2, lane, prefix, kr, cnt_eq);
        radix_small< 0, 4, 1>(sc, h3, lane, prefix, kr, cnt_eq);
        thr = __uint_as_float(prefix);
        tie_rare = (cnt_eq != kr);
        if (tie_rare) {
            #pragma unroll
            for (int i = 0; i < 4; ++i)
                #pragma unroll
                for (int c2 = 0; c2 < 4; ++c2)
                    s_flag[i*1024 + tid*4 + c2] = (sc[i*4+c2] == thr) ? 1 : 0;
            __syncthreads();
            unsigned lc = 0;
            unsigned char mf[16];
            #pragma unroll
            for (int m = 0; m < 16; ++m) { mf[m] = s_flag[tid*16 + m]; lc += mf[m]; }
            s_suf[tid] = lc;
            __syncthreads();
            #pragma unroll
            for (int off = 1; off < 256; off <<= 1) {
                unsigned w = s_suf[tid] + ((tid >= off) ? s_suf[tid - off] : 0u);
                __syncthreads();
                s_suf[tid] = w;
                __syncthreads();
            }
            unsigned r2 = s_suf[tid] - lc;
            #pragma unroll
            for (int m = 0; m < 16; ++m) {
                if (mf[m]) { s_flag[tid*16 + m] = (r2 < kr) ? 2 : 0; ++r2; }
            }
        }
    }
    __syncthreads();                                 // B5: Kth / flags visible
    __builtin_amdgcn_s_setprio(0);                   // selection done
    const unsigned long long Kth64 =
        ((unsigned long long)bin << 32) | (unsigned long long)s_bc[0];

    // ---- gate + store: sigmoid via exp2+raw rcp; hard via one u64 compare ----
    const float A  = -inv_sigma * 1.44269504f;       // exp(-z) = 2^(s*A + Bc)
    const float Bc = -mu * A;
    const unsigned rbase = 1023u - 4u*(unsigned)tid; // 4095-idx = rbase+(3-i)*1024-c2
    #pragma unroll
    for (int i = 0; i < 4; ++i) {
        const float tkc[4] = { tv[i].x, tv[i].y, tv[i].z, tv[i].w };
        f32x4 rv;
        #pragma unroll
        for (int c2 = 0; c2 < 4; ++c2) {
            const float s = sc[i*4+c2];
            const float e2 = __builtin_amdgcn_exp2f(fmaf(s, A, Bc));
            const float soft = __builtin_amdgcn_rcpf(1.0f + e2);
            const unsigned u = __float_as_uint(s);
            bool hard;
            if (cand_mode) {
                const unsigned long long key =
                    ((unsigned long long)(u >> 20) << 32)
                    | (unsigned long long)((u << 12) | (rbase + (3u-(unsigned)i)*1024u - (unsigned)c2));
                hard = (key >= Kth64);
            } else if (tie_rare) {
                hard = (s > thr) || ((s == thr) && (s_flag[i*1024 + tid*4 + c2] == 2));
            } else {
                hard = (s >= thr);
            }
            rv[c2] = tkc[c2] * (hard ? 1.0f : soft);
        }
        __builtin_nontemporal_store(rv, &o4[i*TPB + tid]);
    }
}

extern "C" void kernel_launch(void* const* d_in, const int* in_sizes, int n_in,
                              void* d_out, int out_size, void* d_ws, size_t ws_size,
                              hipStream_t stream) {
    const float* token = (const float*)d_in[0];
    const float* proxy = (const float*)d_in[1];
    float* outp = (float*)d_out;
    const int B = in_sizes[0] / CLS;
    hipLaunchKernelGGL(proxy_gate_kernel, dim3(B), dim3(TPB), 0, stream,
                       token, proxy, outp);
}

// Round 16
// 65.346 us; speedup vs baseline: 1.3137x; 1.0960x over previous
//
#include <hip/hip_runtime.h>
#include <math.h>

#define CLS   4096      // row length C
#define KSEL  2048u     // k = round(C * 0.5)
#define TPB   256

typedef float f32x4 __attribute__((ext_vector_type(4)));

// R10 verbatim — session best (67.5 us). 6-barrier chain, TPB 256, VGPR 60,
// single-copy 12-bit hist, slim exp2/rcp epilogue, u64-key hard mask.
// LDS layout (bytes), total 10304:
//  h0   : u32[2048] @     0 ( 8192)  12-bit hist, single copy, plain layout
//  cand : u32[512]  @  8192 ( 2048)  boundary-bin candidates (packed keys)
//  s_cnt @10240 ; s_wt u32[4] @10244 ; s_bc u32[3] @10260 ; s_fr f32[8] @10272
//  zero region = [0,10240) = 640 uint4 + s_cnt, under global-load latency
//  fallback aliases (h0/cand dead): s_flag u8[4096]@0 ; s_suf u32[256]@4096 ;
//    h1 u32[260]@5120 ; h2 u32[260]@6160 ; h3 u32[64]@7200

template<int SHIFT, int NBITS, int BPL>
__device__ __forceinline__ void radix_small(const float sc[16], unsigned* hist,
        int lane, unsigned& prefix, unsigned& kr, unsigned& cnt_eq)
{
    const unsigned msk = (1u << NBITS) - 1u;
    #pragma unroll
    for (int i = 0; i < 16; ++i) {
        unsigned u = __float_as_uint(sc[i]);
        if ((u >> (SHIFT + NBITS)) == (prefix >> (SHIFT + NBITS)))
            atomicAdd(&hist[(u >> SHIFT) & msk], 1u);
    }
    __syncthreads();
    unsigned c[BPL];
    if constexpr (BPL == 4) {
        uint4 x = *(const uint4*)&hist[lane * 4];
        c[0] = x.x; c[1] = x.y; c[2] = x.z; c[3] = x.w;
    } else {
        c[0] = hist[lane];
    }
    unsigned sfx[BPL + 1]; sfx[BPL] = 0;
    #pragma unroll
    for (int j = BPL - 1; j >= 0; --j) sfx[j] = sfx[j + 1] + c[j];
    const unsigned tot = sfx[0];
    unsigned s = tot;
    #pragma unroll
    for (int off = 1; off < 64; off <<= 1) {
        unsigned t = __shfl_down(s, off);
        if (lane + off < 64) s += t;
    }
    const unsigned Sx = s - tot;
    const bool has = (Sx < kr) && (kr <= Sx + tot);
    unsigned bin = 0, below = 0, ceq = 0;
    if (has) {
        #pragma unroll
        for (int j = 0; j < BPL; ++j)
            if (Sx + sfx[j] >= kr && Sx + sfx[j + 1] < kr) {
                bin = (unsigned)(lane * BPL + j);
                below = Sx + sfx[j + 1];
                ceq = c[j];
            }
    }
    unsigned long long m = __ballot(has);
    int src = (int)__builtin_ctzll(m);
    bin = __shfl(bin, src); below = __shfl(below, src); ceq = __shfl(ceq, src);
    prefix |= bin << SHIFT;
    kr -= below;
    cnt_eq = ceq;
}

__global__ __launch_bounds__(TPB) void proxy_gate_kernel(
    const float* __restrict__ token,
    const float* __restrict__ proxy,
    float* __restrict__ out)
{
    __shared__ __align__(16) unsigned char lds[10304];
    unsigned* h0    = (unsigned*)(lds);
    unsigned* cand  = (unsigned*)(lds + 8192);
    unsigned* s_cnt = (unsigned*)(lds + 10240);
    unsigned* s_wt  = (unsigned*)(lds + 10244);
    unsigned* s_bc  = (unsigned*)(lds + 10260);
    float*    s_fr  = (float*)   (lds + 10272);
    unsigned char* s_flag = lds;                    // fallback aliases (h0 dead)
    unsigned*      s_suf  = (unsigned*)(lds + 4096);
    unsigned*      h1     = (unsigned*)(lds + 5120);
    unsigned*      h2     = (unsigned*)(lds + 6160);
    unsigned*      h3     = (unsigned*)(lds + 7200);

    const int tid  = threadIdx.x;
    const int lane = tid & 63;
    const int wv   = tid >> 6;
    const size_t base = (size_t)blockIdx.x * CLS;
    const float4* t4 = (const float4*)(token + base);
    const float4* p4 = (const float4*)(proxy + base);
    f32x4* o4 = (f32x4*)(out + base);

    // ---- issue all global loads; zero h0+cand (+s_cnt) under their latency ----
    float4 tv[4], pv[4];
    #pragma unroll
    for (int i = 0; i < 4; ++i) { tv[i] = t4[i*TPB + tid]; pv[i] = p4[i*TPB + tid]; }
    {
        uint4 z = make_uint4(0u, 0u, 0u, 0u);
        uint4* zp = (uint4*)lds;
        #pragma unroll
        for (int m = 0; m < 3; ++m) { int idx = m*TPB + tid; if (idx < 640) zp[idx] = z; }
        if (tid == 0) *s_cnt = 0u;
    }

    float sc[16];
    float sum = 0.f, sumsq = 0.f;
    #pragma unroll
    for (int i = 0; i < 4; ++i) {
        float a;
        a = fabsf(tv[i].x*pv[i].x); sc[i*4+0]=a; sum+=a; sumsq+=a*a;
        a = fabsf(tv[i].y*pv[i].y); sc[i*4+1]=a; sum+=a; sumsq+=a*a;
        a = fabsf(tv[i].z*pv[i].z); sc[i*4+2]=a; sum+=a; sumsq+=a*a;
        a = fabsf(tv[i].w*pv[i].w); sc[i*4+3]=a; sum+=a; sumsq+=a*a;
    }
    __syncthreads();                                 // B0: zeroing visible

    // ---- pass 0 atomics (12-bit bins, single copy, plain addr) + stats ----
    #pragma unroll
    for (int i = 0; i < 16; ++i)
        atomicAdd(&h0[__float_as_uint(sc[i]) >> 20], 1u);
    #pragma unroll
    for (int off = 32; off > 0; off >>= 1) {
        sum   += __shfl_xor(sum, off);
        sumsq += __shfl_xor(sumsq, off);
    }
    if (lane == 0) { s_fr[wv] = sum; s_fr[4+wv] = sumsq; }
    __syncthreads();                                 // B1: atomics + stats visible

    const float tot_s = s_fr[0]+s_fr[1]+s_fr[2]+s_fr[3];
    const float tot_q = s_fr[4]+s_fr[5]+s_fr[6]+s_fr[7];
    const float mu = tot_s * (1.0f/CLS);
    float var = (tot_q - tot_s*mu) * (1.0f/(CLS-1));
    var = fmaxf(var, 0.0f);
    const float inv_sigma = 1.0f / fmaxf(sqrtf(var), 1e-6f);

    // ---- pass 0 scan: thread t owns bins [8t,8t+8) ----
    unsigned kr = KSEL;
    {
        uint4 x0 = *(const uint4*)&h0[tid*8];
        uint4 x1 = *(const uint4*)&h0[tid*8 + 4];
        unsigned c[8] = { x0.x, x0.y, x0.z, x0.w, x1.x, x1.y, x1.z, x1.w };
        unsigned sfx[9]; sfx[8] = 0;
        #pragma unroll
        for (int j = 7; j >= 0; --j) sfx[j] = sfx[j+1] + c[j];
        const unsigned tot = sfx[0];
        unsigned s = tot;
        #pragma unroll
        for (int off = 1; off < 64; off <<= 1) {
            unsigned t = __shfl_down(s, off);
            if (lane + off < 64) s += t;
        }
        if (lane == 0) s_wt[wv] = s;
        __syncthreads();                             // B2
        unsigned addhi = 0;
        #pragma unroll
        for (int w2 = 0; w2 < 4; ++w2) if (w2 > wv) addhi += s_wt[w2];
        const unsigned Sx = (s - tot) + addhi;
        if (Sx < kr && kr <= Sx + tot) {
            #pragma unroll
            for (int j = 0; j < 8; ++j)
                if (Sx + sfx[j] >= kr && Sx + sfx[j+1] < kr) {
                    s_bc[0] = (unsigned)(tid*8 + j);
                    s_bc[1] = Sx + sfx[j+1];
                    s_bc[2] = c[j];
                }
        }
        __syncthreads();                             // B3
        kr -= s_bc[1];
    }
    const unsigned bin = s_bc[0];
    unsigned cnt_eq = s_bc[2];

    // ---- gather boundary-bin candidates: key=(u<<12)|(4095-idx), distinct ----
    {
        unsigned cmask = 0, lc = 0;
        #pragma unroll
        for (int ii = 0; ii < 16; ++ii) {
            bool cnd = ((__float_as_uint(sc[ii]) >> 20) == bin);
            cmask |= ((unsigned)cnd) << ii;
            lc += (unsigned)cnd;
        }
        unsigned inc = lc;
        #pragma unroll
        for (int off = 1; off < 64; off <<= 1) {
            unsigned t = __shfl_up(inc, off);
            if (lane >= off) inc += t;
        }
        const unsigned wtot = __shfl(inc, 63);
        unsigned wbase = 0;
        if (lane == 0) wbase = atomicAdd(s_cnt, wtot);
        wbase = __shfl(wbase, 0);
        unsigned p = wbase + (inc - lc);
        #pragma unroll
        for (int ii = 0; ii < 16; ++ii) {
            if ((cmask >> ii) & 1u) {
                unsigned u = __float_as_uint(sc[ii]);
                unsigned idx = (unsigned)((ii >> 2)*1024 + tid*4 + (ii & 3));
                if (p < 512u) cand[p] = (u << 12) | (4095u - idx);
                ++p;
            }
        }
    }
    __syncthreads();                                 // B4
    const unsigned cnt = *s_cnt;
    const bool cand_mode = (cnt <= 512u);

    float thr = 0.f; bool tie_rare = false;
    if (cand_mode) {
        // ---- cooperative rank: thread handles cand slots tid, tid+256 ----
        #pragma unroll
        for (int rpt = 0; rpt < 2; ++rpt) {
            const unsigned slot = (unsigned)tid + (unsigned)rpt*256u;
            if (slot < cnt) {
                const unsigned my = cand[slot];
                unsigned rank = 0;
                const uint4* c4 = (const uint4*)cand;
                const unsigned nq = (cnt + 3u) >> 2;
                for (unsigned q = 0; q < nq; ++q) {  // same-address broadcast reads
                    uint4 v = c4[q];
                    rank += (unsigned)(v.x > my) + (unsigned)(v.y > my)
                          + (unsigned)(v.z > my) + (unsigned)(v.w > my);
                }
                if (rank == kr - 1u) s_bc[0] = my;   // unique: keys distinct
            }
        }
    } else {
        // ---- rare fallback (cnt>512): radix chain + stable tie ranking ----
        unsigned prefix = bin << 20;
        {
            unsigned* hz = (unsigned*)(lds + 5120);  // zero h1/h2/h3 (h0 dead)
            #pragma unroll
            for (int m = 0; m < 3; ++m) { int ix = m*TPB + tid; if (ix < 584) hz[ix] = 0u; }
        }
        __syncthreads();
        radix_small<12, 8, 4>(sc, h1, lane, prefix, kr, cnt_eq);
        radix_small< 4, 8, 4>(sc, h2, lane, prefix, kr, cnt_eq);
        radix_small< 0, 4, 1>(sc, h3, lane, prefix, kr, cnt_eq);
        thr = __uint_as_float(prefix);
        tie_rare = (cnt_eq != kr);
        if (tie_rare) {
            #pragma unroll
            for (int i = 0; i < 4; ++i)
                #pragma unroll
                for (int c2 = 0; c2 < 4; ++c2)
                    s_flag[i*1024 + tid*4 + c2] = (sc[i*4+c2] == thr) ? 1 : 0;
            __syncthreads();
            unsigned lc = 0;
            unsigned char mf[16];
            #pragma unroll
            for (int m = 0; m < 16; ++m) { mf[m] = s_flag[tid*16 + m]; lc += mf[m]; }
            s_suf[tid] = lc;
            __syncthreads();
            #pragma unroll
            for (int off = 1; off < 256; off <<= 1) {
                unsigned w = s_suf[tid] + ((tid >= off) ? s_suf[tid - off] : 0u);
                __syncthreads();
                s_suf[tid] = w;
                __syncthreads();
            }
            unsigned r2 = s_suf[tid] - lc;
            #pragma unroll
            for (int m = 0; m < 16; ++m) {
                if (mf[m]) { s_flag[tid*16 + m] = (r2 < kr) ? 2 : 0; ++r2; }
            }
        }
    }
    __syncthreads();                                 // B5: Kth / flags visible
    const unsigned long long Kth64 =
        ((unsigned long long)bin << 32) | (unsigned long long)s_bc[0];

    // ---- gate + store: sigmoid via exp2+raw rcp; hard via one u64 compare ----
    const float A  = -inv_sigma * 1.44269504f;       // exp(-z) = 2^(s*A + Bc)
    const float Bc = -mu * A;
    const unsigned rbase = 1023u - 4u*(unsigned)tid; // 4095-idx = rbase+(3-i)*1024-c2
    #pragma unroll
    for (int i = 0; i < 4; ++i) {
        const float tkc[4] = { tv[i].x, tv[i].y, tv[i].z, tv[i].w };
        f32x4 rv;
        #pragma unroll
        for (int c2 = 0; c2 < 4; ++c2) {
            const float s = sc[i*4+c2];
            const float e2 = __builtin_amdgcn_exp2f(fmaf(s, A, Bc));
            const float soft = __builtin_amdgcn_rcpf(1.0f + e2);
            const unsigned u = __float_as_uint(s);
            bool hard;
            if (cand_mode) {
                const unsigned long long key =
                    ((unsigned long long)(u >> 20) << 32)
                    | (unsigned long long)((u << 12) | (rbase + (3u-(unsigned)i)*1024u - (unsigned)c2));
                hard = (key >= Kth64);
            } else if (tie_rare) {
                hard = (s > thr) || ((s == thr) && (s_flag[i*1024 + tid*4 + c2] == 2));
            } else {
                hard = (s >= thr);
            }
            rv[c2] = tkc[c2] * (hard ? 1.0f : soft);
        }
        __builtin_nontemporal_store(rv, &o4[i*TPB + tid]);
    }
}

extern "C" void kernel_launch(void* const* d_in, const int* in_sizes, int n_in,
                              void* d_out, int out_size, void* d_ws, size_t ws_size,
                              hipStream_t stream) {
    const float* token = (const float*)d_in[0];
    const float* proxy = (const float*)d_in[1];
    float* outp = (float*)d_out;
    const int B = in_sizes[0] / CLS;
    hipLaunchKernelGGL(proxy_gate_kernel, dim3(B), dim3(TPB), 0, stream,
                       token, proxy, outp);
}